// Round 4
// baseline (147.038 us; speedup 1.0000x reference)
//
#include <hip/hip_runtime.h>

// GnnLayer: out[50000,64] = leaky_relu((h[idx]/dist).reshape(N,2048) @ W + bias)
// v5: v4's duplication-free kg8 wave split (B = 4KB/node global reads, half of
// v3) but register-dieted so 2 blocks (16 waves) stay resident per CU:
//  - no explicit next-kn prefetch array (rely on 16-wave TLP + compiler sched)
//  - A loaded per-jh (A[4] live instead of A[4][2]+NA[4][2])
//  - __launch_bounds__(512,4) caps VGPR at 128 (4 waves/SIMD)
// Barrier-free main loop; 4-stage pairwise cross-wave K-reduction in LDS.
// ws layout: [0, 256KB) = W fragments f16; [256KB, +6.4MB) = h f16 [50000][64]

#define N_NODES 50000
#define KN      32
#define FIN     64
#define FOUT    64
#define MTILE   64

typedef __attribute__((ext_vector_type(4))) float    f32x4;
typedef __attribute__((ext_vector_type(8))) _Float16 f16x8;
typedef __attribute__((ext_vector_type(4))) _Float16 f16x4;

// Merged prep: blocks [0,64) convert W -> fragment-ordered f16; blocks [64,..)
// convert h fp32 -> f16 (coalesced float4 -> f16x4).
__global__ void k_prep(const float* __restrict__ w, _Float16* __restrict__ wf,
                       const float* __restrict__ h, _Float16* __restrict__ hb) {
    __shared__ float s_w[32 * 64];
    const int tid = threadIdx.x;
    if (blockIdx.x < 64) {
        // wf[kk*2048 + t*512 + lane*8 + i] = W[kk*32 + (lane>>4)*8 + i][t*16 + (lane&15)]
        const int kk = blockIdx.x;
        for (int p = tid; p < 32 * 64; p += 256)
            s_w[p] = w[kk * 32 * 64 + p];
        __syncthreads();
        const int t = tid >> 6, lane = tid & 63;
        const int lm = lane & 15, q = lane >> 4;
        f16x8 o;
        #pragma unroll
        for (int i = 0; i < 8; ++i)
            o[i] = (_Float16)s_w[(q * 8 + i) * 64 + t * 16 + lm];
        *(f16x8*)(wf + kk * 2048 + t * 512 + lane * 8) = o;
    } else {
        const int i = (blockIdx.x - 64) * 256 + tid;  // 800000 float4s
        float4 v = ((const float4*)h)[i];
        f16x4 o = { (_Float16)v.x, (_Float16)v.y, (_Float16)v.z, (_Float16)v.w };
        ((f16x4*)hb)[i] = o;
    }
}

__global__ __launch_bounds__(512, 4) void k_main(
        const _Float16* __restrict__ hf,    // f16 h [N][64]
        const float*    __restrict__ pos,   // [N][3]
        const int*      __restrict__ nidx,  // [N][32]
        const _Float16* __restrict__ wf,    // f16 W fragments
        const float*    __restrict__ bias,  // [64]
        float*          __restrict__ out)   // [N][64]
{
    __shared__ int2  s_e[KN * MTILE];     // [kn][m] {idx, scl bits}, 16 KB
    __shared__ float s_red[2 * 64 * 68];  // 2 reduction regions, 34 KB

    const int tid = threadIdx.x;
    const int m0  = blockIdx.x * MTILE;

    // Phase 0: per-edge {neighbor idx, 1/dist}. m = p&63 -> conflict-free writes.
    for (int p = tid; p < MTILE * KN; p += 512) {
        int m = p & 63, k = p >> 6;
        int node = m0 + m;
        int idx = 0; float scl = 0.f;
        if (node < N_NODES) {
            idx = nidx[node * KN + k];
            float dx = pos[node * 3 + 0] - pos[idx * 3 + 0];
            float dy = pos[node * 3 + 1] - pos[idx * 3 + 1];
            float dz = pos[node * 3 + 2] - pos[idx * 3 + 2];
            float sq = dx * dx + dy * dy + dz * dz;
            scl = (sq == 0.f) ? 2.0f : rsqrtf(sq);  // ref: dist=0.5 when sq==0
        }
        s_e[k * MTILE + m] = make_int2(idx, __float_as_int(scl));
    }
    __syncthreads();

    const int lane = tid & 63, kg = tid >> 6;   // wave kg: kn in [kg*4, kg*4+4)
    const int lm = lane & 15, q = lane >> 4;

    const _Float16* pb = wf + lane * 8;
    const int ebase = (kg * 4) * MTILE + lm;

    f32x4 acc[4][4] = {};  // [m-tile][n-tile]: 64 nodes x 64 cols, K-partial

    #pragma unroll
    for (int j = 0; j < 4; ++j) {
        // Edge metadata for this kn (4 m-tiles), then per-jh A loads.
        const _Float16* pa[4];
        _Float16 sc[4];
        #pragma unroll
        for (int mt = 0; mt < 4; ++mt) {
            int2 e = s_e[ebase + j * MTILE + mt * 16];
            pa[mt] = hf + e.x * FIN + q * 8;
            sc[mt] = (_Float16)__int_as_float(e.y);
        }

        const int kn = kg * 4 + j;
        #pragma unroll
        for (int jh = 0; jh < 2; ++jh) {
            const _Float16* pbb = pb + (kn * 2 + jh) * 2048;
            f16x8 b0 = *(const f16x8*)(pbb);
            f16x8 b1 = *(const f16x8*)(pbb + 512);
            f16x8 b2 = *(const f16x8*)(pbb + 1024);
            f16x8 b3 = *(const f16x8*)(pbb + 1536);
            #pragma unroll
            for (int mt = 0; mt < 4; ++mt) {
                f16x8 a = *(const f16x8*)(pa[mt] + jh * 32) * sc[mt];  // v_pk_mul_f16 x4
                acc[mt][0] = __builtin_amdgcn_mfma_f32_16x16x32_f16(a, b0, acc[mt][0], 0, 0, 0);
                acc[mt][1] = __builtin_amdgcn_mfma_f32_16x16x32_f16(a, b1, acc[mt][1], 0, 0, 0);
                acc[mt][2] = __builtin_amdgcn_mfma_f32_16x16x32_f16(a, b2, acc[mt][2], 0, 0, 0);
                acc[mt][3] = __builtin_amdgcn_mfma_f32_16x16x32_f16(a, b3, acc[mt][3], 0, 0, 0);
            }
        }
    }

    // 4-stage pairwise cross-wave K-reduction (8 partials -> 2 regions).
    // C/D layout: col = lane&15 (n), row = q*4 + r. Global row = mt*16 + row.
    float* reg = s_red + (kg & 1) * (64 * 68);
    if (kg < 2) {
        #pragma unroll
        for (int mt = 0; mt < 4; ++mt)
            #pragma unroll
            for (int t = 0; t < 4; ++t)
                #pragma unroll
                for (int r = 0; r < 4; ++r)
                    reg[(mt * 16 + q * 4 + r) * 68 + t * 16 + lm] = acc[mt][t][r];
    }
    __syncthreads();
    if (kg >= 2 && kg < 4) {
        #pragma unroll
        for (int mt = 0; mt < 4; ++mt)
            #pragma unroll
            for (int t = 0; t < 4; ++t)
                #pragma unroll
                for (int r = 0; r < 4; ++r)
                    reg[(mt * 16 + q * 4 + r) * 68 + t * 16 + lm] += acc[mt][t][r];
    }
    __syncthreads();
    if (kg >= 4 && kg < 6) {
        #pragma unroll
        for (int mt = 0; mt < 4; ++mt)
            #pragma unroll
            for (int t = 0; t < 4; ++t)
                #pragma unroll
                for (int r = 0; r < 4; ++r)
                    reg[(mt * 16 + q * 4 + r) * 68 + t * 16 + lm] += acc[mt][t][r];
    }
    __syncthreads();
    if (kg >= 6) {
        #pragma unroll
        for (int mt = 0; mt < 4; ++mt)
            #pragma unroll
            for (int t = 0; t < 4; ++t)
                #pragma unroll
                for (int r = 0; r < 4; ++r)
                    reg[(mt * 16 + q * 4 + r) * 68 + t * 16 + lm] += acc[mt][t][r];
    }
    __syncthreads();

    // Epilogue: region0 + region1 + bias, leaky_relu, coalesced f32x4 stores.
    const int row = tid >> 3, c0 = (tid & 7) * 8;
    const int node = m0 + row;
    if (node < N_NODES) {
        #pragma unroll
        for (int i = 0; i < 2; ++i) {
            int c = c0 + i * 4;
            f32x4 v0 = *(const f32x4*)(s_red + row * 68 + c);
            f32x4 v1 = *(const f32x4*)(s_red + 64 * 68 + row * 68 + c);
            f32x4 bb = *(const f32x4*)(bias + c);
            f32x4 o = v0 + v1 + bb;
            #pragma unroll
            for (int j = 0; j < 4; ++j) o[j] = o[j] > 0.f ? o[j] : 0.01f * o[j];
            *(f32x4*)(out + node * FOUT + c) = o;
        }
    }
}

extern "C" void kernel_launch(void* const* d_in, const int* in_sizes, int n_in,
                              void* d_out, int out_size, void* d_ws, size_t ws_size,
                              hipStream_t stream) {
    const float* h    = (const float*)d_in[0];
    const float* pos  = (const float*)d_in[1];
    const int*   nidx = (const int*)d_in[2];
    const float* w    = (const float*)d_in[3];
    const float* bias = (const float*)d_in[4];
    float* out = (float*)d_out;

    _Float16* wf = (_Float16*)d_ws;                      // 256 KB (fragment-ordered W)
    _Float16* hb = (_Float16*)((char*)d_ws + 262144);    // 6.4 MB (h in f16)

    k_prep<<<64 + (N_NODES * FIN / 4) / 256, 256, 0, stream>>>(w, wf, h, hb);
    k_main<<<(N_NODES + MTILE - 1) / MTILE, 512, 0, stream>>>(hb, pos, nidx, wf, bias, out);
}

// Round 6
// 128.867 us; speedup vs baseline: 1.1410x; 1.1410x over previous
//
#include <hip/hip_runtime.h>

// GnnLayer: out[50000,64] = leaky_relu((h[idx]/dist).reshape(N,2048) @ W + bias)
// v6: duplication-free B topology, spill-free + occupied this time.
//  - 256-thread blocks (4 waves), MTILE=64. Wave kg in {0..3} computes ALL 64
//    nodes x K-slice of 512 (kn in [kg*8, kg*8+8)). B read exactly once per
//    block (4KB/node); A gathers are the algorithmic floor (4KB/node).
//  - #pragma unroll 1 on the kn loop + per-jh A loads: keeps live set ~116 regs
//    so __launch_bounds__(256,4) (128-reg cap) does NOT spill (v5 lesson:
//    WRITE_SIZE is the spill tripwire).
//  - LDS union: s_e (16KB) aliases s_red (34.8KB), barrier-separated ->
//    34.8KB/block -> 4 blocks/CU -> 16 waves/CU.
//  - 2-stage pairwise cross-wave reduction (4 partials -> 2 regions -> out).
// ws layout: [0, 256KB) = W fragments f16; [256KB, +6.4MB) = h f16 [50000][64]

#define N_NODES 50000
#define KN      32
#define FIN     64
#define FOUT    64
#define MTILE   64

typedef __attribute__((ext_vector_type(4))) float    f32x4;
typedef __attribute__((ext_vector_type(8))) _Float16 f16x8;
typedef __attribute__((ext_vector_type(4))) _Float16 f16x4;

// Merged prep: blocks [0,64) convert W -> fragment-ordered f16; blocks [64,..)
// convert h fp32 -> f16 (coalesced float4 -> f16x4).
__global__ void k_prep(const float* __restrict__ w, _Float16* __restrict__ wf,
                       const float* __restrict__ h, _Float16* __restrict__ hb) {
    __shared__ float s_w[32 * 64];
    const int tid = threadIdx.x;
    if (blockIdx.x < 64) {
        // wf[kk*2048 + t*512 + lane*8 + i] = W[kk*32 + (lane>>4)*8 + i][t*16 + (lane&15)]
        const int kk = blockIdx.x;
        for (int p = tid; p < 32 * 64; p += 256)
            s_w[p] = w[kk * 32 * 64 + p];
        __syncthreads();
        const int t = tid >> 6, lane = tid & 63;
        const int lm = lane & 15, q = lane >> 4;
        f16x8 o;
        #pragma unroll
        for (int i = 0; i < 8; ++i)
            o[i] = (_Float16)s_w[(q * 8 + i) * 64 + t * 16 + lm];
        *(f16x8*)(wf + kk * 2048 + t * 512 + lane * 8) = o;
    } else {
        const int i = (blockIdx.x - 64) * 256 + tid;  // 800000 float4s
        float4 v = ((const float4*)h)[i];
        f16x4 o = { (_Float16)v.x, (_Float16)v.y, (_Float16)v.z, (_Float16)v.w };
        ((f16x4*)hb)[i] = o;
    }
}

__global__ __launch_bounds__(256, 4) void k_main(
        const _Float16* __restrict__ hf,    // f16 h [N][64]
        const float*    __restrict__ pos,   // [N][3]
        const int*      __restrict__ nidx,  // [N][32]
        const _Float16* __restrict__ wf,    // f16 W fragments
        const float*    __restrict__ bias,  // [64]
        float*          __restrict__ out)   // [N][64]
{
    // Union: phase 0 + main loop use s_e (16KB); reduction reuses the same
    // memory as s_red (34.8KB). Separated by __syncthreads().
    __shared__ __align__(16) char smem[2 * 64 * 68 * 4];
    int2*  s_e   = (int2*)smem;            // [kn][m] {idx, scl bits}
    float* s_red = (float*)smem;           // 2 regions of [64][68]

    const int tid = threadIdx.x;
    const int m0  = blockIdx.x * MTILE;

    // Phase 0: per-edge {neighbor idx, 1/dist}. m = p&63 -> conflict-free writes.
    for (int p = tid; p < MTILE * KN; p += 256) {
        int m = p & 63, k = p >> 6;
        int node = m0 + m;
        int idx = 0; float scl = 0.f;
        if (node < N_NODES) {
            idx = nidx[node * KN + k];
            float dx = pos[node * 3 + 0] - pos[idx * 3 + 0];
            float dy = pos[node * 3 + 1] - pos[idx * 3 + 1];
            float dz = pos[node * 3 + 2] - pos[idx * 3 + 2];
            float sq = dx * dx + dy * dy + dz * dz;
            scl = (sq == 0.f) ? 2.0f : rsqrtf(sq);  // ref: dist=0.5 when sq==0
        }
        s_e[k * MTILE + m] = make_int2(idx, __float_as_int(scl));
    }
    __syncthreads();

    const int lane = tid & 63, kg = tid >> 6;   // wave kg: kn in [kg*8, kg*8+8)
    const int lm = lane & 15, q = lane >> 4;

    const _Float16* pb = wf + lane * 8;

    f32x4 acc[4][4] = {};  // [m-tile][n-tile]: 64 nodes x 64 cols, K-partial

    #pragma unroll 1
    for (int j = 0; j < 8; ++j) {
        const int kn = kg * 8 + j;
        // Edge metadata for this kn (4 m-tiles).
        int2 e0 = s_e[kn * MTILE + lm];
        int2 e1 = s_e[kn * MTILE + 16 + lm];
        int2 e2 = s_e[kn * MTILE + 32 + lm];
        int2 e3 = s_e[kn * MTILE + 48 + lm];
        const _Float16* pa0 = hf + e0.x * FIN + q * 8;
        const _Float16* pa1 = hf + e1.x * FIN + q * 8;
        const _Float16* pa2 = hf + e2.x * FIN + q * 8;
        const _Float16* pa3 = hf + e3.x * FIN + q * 8;
        const _Float16 s0 = (_Float16)__int_as_float(e0.y);
        const _Float16 s1 = (_Float16)__int_as_float(e1.y);
        const _Float16 s2 = (_Float16)__int_as_float(e2.y);
        const _Float16 s3 = (_Float16)__int_as_float(e3.y);

        #pragma unroll
        for (int jh = 0; jh < 2; ++jh) {
            const _Float16* pbb = pb + (kn * 2 + jh) * 2048;
            f16x8 b0 = *(const f16x8*)(pbb);
            f16x8 b1 = *(const f16x8*)(pbb + 512);
            f16x8 b2 = *(const f16x8*)(pbb + 1024);
            f16x8 b3 = *(const f16x8*)(pbb + 1536);
            f16x8 a0 = *(const f16x8*)(pa0 + jh * 32) * s0;  // v_pk_mul_f16 x4
            f16x8 a1 = *(const f16x8*)(pa1 + jh * 32) * s1;
            f16x8 a2 = *(const f16x8*)(pa2 + jh * 32) * s2;
            f16x8 a3 = *(const f16x8*)(pa3 + jh * 32) * s3;
            acc[0][0] = __builtin_amdgcn_mfma_f32_16x16x32_f16(a0, b0, acc[0][0], 0, 0, 0);
            acc[0][1] = __builtin_amdgcn_mfma_f32_16x16x32_f16(a0, b1, acc[0][1], 0, 0, 0);
            acc[0][2] = __builtin_amdgcn_mfma_f32_16x16x32_f16(a0, b2, acc[0][2], 0, 0, 0);
            acc[0][3] = __builtin_amdgcn_mfma_f32_16x16x32_f16(a0, b3, acc[0][3], 0, 0, 0);
            acc[1][0] = __builtin_amdgcn_mfma_f32_16x16x32_f16(a1, b0, acc[1][0], 0, 0, 0);
            acc[1][1] = __builtin_amdgcn_mfma_f32_16x16x32_f16(a1, b1, acc[1][1], 0, 0, 0);
            acc[1][2] = __builtin_amdgcn_mfma_f32_16x16x32_f16(a1, b2, acc[1][2], 0, 0, 0);
            acc[1][3] = __builtin_amdgcn_mfma_f32_16x16x32_f16(a1, b3, acc[1][3], 0, 0, 0);
            acc[2][0] = __builtin_amdgcn_mfma_f32_16x16x32_f16(a2, b0, acc[2][0], 0, 0, 0);
            acc[2][1] = __builtin_amdgcn_mfma_f32_16x16x32_f16(a2, b1, acc[2][1], 0, 0, 0);
            acc[2][2] = __builtin_amdgcn_mfma_f32_16x16x32_f16(a2, b2, acc[2][2], 0, 0, 0);
            acc[2][3] = __builtin_amdgcn_mfma_f32_16x16x32_f16(a2, b3, acc[2][3], 0, 0, 0);
            acc[3][0] = __builtin_amdgcn_mfma_f32_16x16x32_f16(a3, b0, acc[3][0], 0, 0, 0);
            acc[3][1] = __builtin_amdgcn_mfma_f32_16x16x32_f16(a3, b1, acc[3][1], 0, 0, 0);
            acc[3][2] = __builtin_amdgcn_mfma_f32_16x16x32_f16(a3, b2, acc[3][2], 0, 0, 0);
            acc[3][3] = __builtin_amdgcn_mfma_f32_16x16x32_f16(a3, b3, acc[3][3], 0, 0, 0);
        }
    }

    // Main loop done reading s_e; barrier before aliased s_red writes.
    __syncthreads();

    // 2-stage pairwise cross-wave K-reduction (4 partials -> 2 regions).
    // C/D layout: col = lane&15 (n), row = q*4 + r. Global row = mt*16 + row.
    float* reg = s_red + (kg & 1) * (64 * 68);
    if (kg < 2) {
        #pragma unroll
        for (int mt = 0; mt < 4; ++mt)
            #pragma unroll
            for (int t = 0; t < 4; ++t)
                #pragma unroll
                for (int r = 0; r < 4; ++r)
                    reg[(mt * 16 + q * 4 + r) * 68 + t * 16 + lm] = acc[mt][t][r];
    }
    __syncthreads();
    if (kg >= 2) {
        #pragma unroll
        for (int mt = 0; mt < 4; ++mt)
            #pragma unroll
            for (int t = 0; t < 4; ++t)
                #pragma unroll
                for (int r = 0; r < 4; ++r)
                    reg[(mt * 16 + q * 4 + r) * 68 + t * 16 + lm] += acc[mt][t][r];
    }
    __syncthreads();

    // Epilogue: region0 + region1 + bias, leaky_relu, coalesced f32x4 stores.
    const int row = tid >> 2, c0 = (tid & 3) * 16;
    const int node = m0 + row;
    if (node < N_NODES) {
        #pragma unroll
        for (int i = 0; i < 4; ++i) {
            int c = c0 + i * 4;
            f32x4 v0 = *(const f32x4*)(s_red + row * 68 + c);
            f32x4 v1 = *(const f32x4*)(s_red + 64 * 68 + row * 68 + c);
            f32x4 bb = *(const f32x4*)(bias + c);
            f32x4 o = v0 + v1 + bb;
            #pragma unroll
            for (int jj = 0; jj < 4; ++jj) o[jj] = o[jj] > 0.f ? o[jj] : 0.01f * o[jj];
            *(f32x4*)(out + node * FOUT + c) = o;
        }
    }
}

extern "C" void kernel_launch(void* const* d_in, const int* in_sizes, int n_in,
                              void* d_out, int out_size, void* d_ws, size_t ws_size,
                              hipStream_t stream) {
    const float* h    = (const float*)d_in[0];
    const float* pos  = (const float*)d_in[1];
    const int*   nidx = (const int*)d_in[2];
    const float* w    = (const float*)d_in[3];
    const float* bias = (const float*)d_in[4];
    float* out = (float*)d_out;

    _Float16* wf = (_Float16*)d_ws;                      // 256 KB (fragment-ordered W)
    _Float16* hb = (_Float16*)((char*)d_ws + 262144);    // 6.4 MB (h in f16)

    k_prep<<<64 + (N_NODES * FIN / 4) / 256, 256, 0, stream>>>(w, wf, h, hb);
    k_main<<<(N_NODES + MTILE - 1) / MTILE, 256, 0, stream>>>(hb, pos, nidx, wf, bias, out);
}

// Round 10
// 115.479 us; speedup vs baseline: 1.2733x; 1.1159x over previous
//
#include <hip/hip_runtime.h>

// GnnLayer: out[50000,64] = leaky_relu((h[idx]/dist).reshape(N,2048) @ W + bias)
// v8: shared-scale int8 h (accuracy-safe replacement for v7's failed fp8).
//  - h row stored as 64 x int8 with per-row scale = amax/126 -> 64B row, ONE
//    cache line per edge; h total 3.2MB -> per-XCD-L2-resident.
//  - Exact decode: byte b=q+128; f16 bits (0x6400|(4b)) == 1024+4b exactly;
//    (x - 1536) == 4q exactly; one rounding at the final mul by
//    c1 = scale * (1/dist) / 4 (f32 in phase 0, one f16 cvt per edge).
//  - posx[n] = {x,y,z,scale} float4: pos + scale gathered in ONE aligned 16B
//    request per edge (also kills pos's 12B line-split penalty).
//  - Otherwise v6 structure: 256 thr / 4 waves / kg4 split, barrier-free main
//    loop, #pragma unroll 1 (spill guard), LDS union, 2-stage reduction.
// ws: [0,256KB) W frags f16; [256KB,+3.2MB) h int8; then posx [N]x16B.

#define N_NODES 50000
#define KN      32
#define FIN     64
#define FOUT    64
#define MTILE   64

typedef __attribute__((ext_vector_type(4))) float    f32x4;
typedef __attribute__((ext_vector_type(8))) _Float16 f16x8;

// 8 int8 features (two uints) -> f16x8 of (1024 + 4*b); caller subtracts 1536
// and multiplies by c1. Plain shift/mask (no perm-semantics risk).
static __device__ __forceinline__ f16x8 dec8i(unsigned int x, unsigned int y) {
    union { unsigned int w[4]; f16x8 v; } r;
    unsigned int xh = x >> 16, yh = y >> 16;
    r.w[0] = 0x64006400u | ((x  & 0xFFu) << 2) | ((x  & 0xFF00u) << 10);
    r.w[1] = 0x64006400u | ((xh & 0xFFu) << 2) | ((xh & 0xFF00u) << 10);
    r.w[2] = 0x64006400u | ((y  & 0xFFu) << 2) | ((y  & 0xFF00u) << 10);
    r.w[3] = 0x64006400u | ((yh & 0xFFu) << 2) | ((yh & 0xFF00u) << 10);
    return r.v;
}

// Prep: blocks [0,32) -> W fragments f16 (v7 K-order, no scaling);
// blocks [32,32+196) -> per-row int8 quantization of h + packed posx.
__global__ void k_prep(const float* __restrict__ w, _Float16* __restrict__ wf,
                       const float* __restrict__ h, unsigned char* __restrict__ hq,
                       const float* __restrict__ pos, float4* __restrict__ posx) {
    __shared__ float s_w[64 * 64];
    const int tid = threadIdx.x;
    if (blockIdx.x < 32) {
        // wf[((kn*2+jh)*4 + t)*512 + lane*8 + i]
        //   = W[kn*64 + q*16 + jh*8 + i][t*16 + lm],  q=lane>>4, lm=lane&15
        const int kn = blockIdx.x;
        for (int p = tid; p < 64 * 64; p += 256)
            s_w[p] = w[kn * 64 * 64 + p];
        __syncthreads();
        const int t = tid >> 6, lane = tid & 63;
        const int lm = lane & 15, q = lane >> 4;
        #pragma unroll
        for (int jh = 0; jh < 2; ++jh) {
            f16x8 o;
            #pragma unroll
            for (int i = 0; i < 8; ++i)
                o[i] = (_Float16)s_w[(q * 16 + jh * 8 + i) * 64 + t * 16 + lm];
            *(f16x8*)(wf + ((kn * 2 + jh) * 4 + t) * 512 + lane * 8) = o;
        }
    } else {
        const int r = (blockIdx.x - 32) * 256 + tid;   // one node per thread
        if (r < N_NODES) {
            const float* hr = h + (size_t)r * FIN;
            float v[64];
            float amax = 0.f;
            #pragma unroll
            for (int i = 0; i < 16; ++i) {
                float4 t4 = ((const float4*)hr)[i];
                v[i * 4 + 0] = t4.x; v[i * 4 + 1] = t4.y;
                v[i * 4 + 2] = t4.z; v[i * 4 + 3] = t4.w;
                amax = fmaxf(amax, fmaxf(fmaxf(fabsf(t4.x), fabsf(t4.y)),
                                         fmaxf(fabsf(t4.z), fabsf(t4.w))));
            }
            float scale = fmaxf(amax, 1e-30f) * (1.0f / 126.0f);
            float inv = 126.0f / fmaxf(amax, 1e-30f);
            union { unsigned char c[64]; uint4 u4[4]; } o;
            #pragma unroll
            for (int i = 0; i < 64; ++i) {
                int q8 = __float2int_rn(v[i] * inv);          // [-126,126]
                o.c[i] = (unsigned char)(q8 + 128);
            }
            uint4* dst = (uint4*)(hq + (size_t)r * 64);
            dst[0] = o.u4[0]; dst[1] = o.u4[1]; dst[2] = o.u4[2]; dst[3] = o.u4[3];
            float4 px;
            px.x = pos[r * 3 + 0]; px.y = pos[r * 3 + 1]; px.z = pos[r * 3 + 2];
            px.w = scale;
            posx[r] = px;
        }
    }
}

__global__ __launch_bounds__(256, 4) void k_main(
        const unsigned char* __restrict__ hq,   // int8 h [N][64]
        const float4*        __restrict__ posx, // [N] {x,y,z,scale}
        const int*           __restrict__ nidx, // [N][32]
        const _Float16*      __restrict__ wf,   // f16 W fragments
        const float*         __restrict__ bias, // [64]
        float*               __restrict__ out)  // [N][64]
{
    // Union: phase 0 + main loop use s_e (16KB); reduction reuses as s_red.
    __shared__ __align__(16) char smem[2 * 64 * 68 * 4];
    int2*  s_e   = (int2*)smem;            // [kn][m] {idx, c1 bits (f32)}
    float* s_red = (float*)smem;           // 2 regions of [64][68]

    const int tid = threadIdx.x;
    const int m0  = blockIdx.x * MTILE;

    // Phase 0: per-edge {neighbor idx, c1 = scale*(1/dist)/4}.
    for (int p = tid; p < MTILE * KN; p += 256) {
        int m = p & 63, k = p >> 6;
        int node = m0 + m;
        int idx = 0; float c1 = 0.f;
        if (node < N_NODES) {
            idx = nidx[node * KN + k];
            float4 pn = posx[node];
            float4 pi = posx[idx];
            float dx = pn.x - pi.x, dy = pn.y - pi.y, dz = pn.z - pi.z;
            float sq = dx * dx + dy * dy + dz * dz;
            float scl = (sq == 0.f) ? 2.0f : rsqrtf(sq);  // ref: dist=0.5 at sq==0
            c1 = pi.w * scl * 0.25f;
        }
        s_e[k * MTILE + m] = make_int2(idx, __float_as_int(c1));
    }
    __syncthreads();

    const int lane = tid & 63, kg = tid >> 6;   // wave kg: kn in [kg*8, kg*8+8)
    const int lm = lane & 15, q = lane >> 4;

    const _Float16* pb = wf + lane * 8;

    f32x4 acc[4][4] = {};  // [m-tile][n-tile]

    #pragma unroll 1
    for (int j = 0; j < 8; ++j) {
        const int kn = kg * 8 + j;
        int2 e0 = s_e[kn * MTILE + lm];
        int2 e1 = s_e[kn * MTILE + 16 + lm];
        int2 e2 = s_e[kn * MTILE + 32 + lm];
        int2 e3 = s_e[kn * MTILE + 48 + lm];
        // ONE 16B load per edge: features q*16 .. q*16+16 (covers both jh).
        uint4 d0 = *(const uint4*)(hq + (size_t)e0.x * 64 + q * 16);
        uint4 d1 = *(const uint4*)(hq + (size_t)e1.x * 64 + q * 16);
        uint4 d2 = *(const uint4*)(hq + (size_t)e2.x * 64 + q * 16);
        uint4 d3 = *(const uint4*)(hq + (size_t)e3.x * 64 + q * 16);
        const _Float16 c0 = (_Float16)__int_as_float(e0.y);
        const _Float16 c1 = (_Float16)__int_as_float(e1.y);
        const _Float16 c2 = (_Float16)__int_as_float(e2.y);
        const _Float16 c3 = (_Float16)__int_as_float(e3.y);
        const _Float16 K = (_Float16)1536.0f;

        {   // jh = 0: features q*16 + 0..8 (bytes d.x, d.y)
            const _Float16* pbb = pb + (kn * 2 + 0) * 2048;
            f16x8 b0 = *(const f16x8*)(pbb);
            f16x8 b1 = *(const f16x8*)(pbb + 512);
            f16x8 b2 = *(const f16x8*)(pbb + 1024);
            f16x8 b3 = *(const f16x8*)(pbb + 1536);
            f16x8 a0 = (dec8i(d0.x, d0.y) - K) * c0;
            f16x8 a1 = (dec8i(d1.x, d1.y) - K) * c1;
            f16x8 a2 = (dec8i(d2.x, d2.y) - K) * c2;
            f16x8 a3 = (dec8i(d3.x, d3.y) - K) * c3;
            acc[0][0] = __builtin_amdgcn_mfma_f32_16x16x32_f16(a0, b0, acc[0][0], 0, 0, 0);
            acc[0][1] = __builtin_amdgcn_mfma_f32_16x16x32_f16(a0, b1, acc[0][1], 0, 0, 0);
            acc[0][2] = __builtin_amdgcn_mfma_f32_16x16x32_f16(a0, b2, acc[0][2], 0, 0, 0);
            acc[0][3] = __builtin_amdgcn_mfma_f32_16x16x32_f16(a0, b3, acc[0][3], 0, 0, 0);
            acc[1][0] = __builtin_amdgcn_mfma_f32_16x16x32_f16(a1, b0, acc[1][0], 0, 0, 0);
            acc[1][1] = __builtin_amdgcn_mfma_f32_16x16x32_f16(a1, b1, acc[1][1], 0, 0, 0);
            acc[1][2] = __builtin_amdgcn_mfma_f32_16x16x32_f16(a1, b2, acc[1][2], 0, 0, 0);
            acc[1][3] = __builtin_amdgcn_mfma_f32_16x16x32_f16(a1, b3, acc[1][3], 0, 0, 0);
            acc[2][0] = __builtin_amdgcn_mfma_f32_16x16x32_f16(a2, b0, acc[2][0], 0, 0, 0);
            acc[2][1] = __builtin_amdgcn_mfma_f32_16x16x32_f16(a2, b1, acc[2][1], 0, 0, 0);
            acc[2][2] = __builtin_amdgcn_mfma_f32_16x16x32_f16(a2, b2, acc[2][2], 0, 0, 0);
            acc[2][3] = __builtin_amdgcn_mfma_f32_16x16x32_f16(a2, b3, acc[2][3], 0, 0, 0);
            acc[3][0] = __builtin_amdgcn_mfma_f32_16x16x32_f16(a3, b0, acc[3][0], 0, 0, 0);
            acc[3][1] = __builtin_amdgcn_mfma_f32_16x16x32_f16(a3, b1, acc[3][1], 0, 0, 0);
            acc[3][2] = __builtin_amdgcn_mfma_f32_16x16x32_f16(a3, b2, acc[3][2], 0, 0, 0);
            acc[3][3] = __builtin_amdgcn_mfma_f32_16x16x32_f16(a3, b3, acc[3][3], 0, 0, 0);
        }
        {   // jh = 1: features q*16 + 8..16 (bytes d.z, d.w)
            const _Float16* pbb = pb + (kn * 2 + 1) * 2048;
            f16x8 b0 = *(const f16x8*)(pbb);
            f16x8 b1 = *(const f16x8*)(pbb + 512);
            f16x8 b2 = *(const f16x8*)(pbb + 1024);
            f16x8 b3 = *(const f16x8*)(pbb + 1536);
            f16x8 a0 = (dec8i(d0.z, d0.w) - K) * c0;
            f16x8 a1 = (dec8i(d1.z, d1.w) - K) * c1;
            f16x8 a2 = (dec8i(d2.z, d2.w) - K) * c2;
            f16x8 a3 = (dec8i(d3.z, d3.w) - K) * c3;
            acc[0][0] = __builtin_amdgcn_mfma_f32_16x16x32_f16(a0, b0, acc[0][0], 0, 0, 0);
            acc[0][1] = __builtin_amdgcn_mfma_f32_16x16x32_f16(a0, b1, acc[0][1], 0, 0, 0);
            acc[0][2] = __builtin_amdgcn_mfma_f32_16x16x32_f16(a0, b2, acc[0][2], 0, 0, 0);
            acc[0][3] = __builtin_amdgcn_mfma_f32_16x16x32_f16(a0, b3, acc[0][3], 0, 0, 0);
            acc[1][0] = __builtin_amdgcn_mfma_f32_16x16x32_f16(a1, b0, acc[1][0], 0, 0, 0);
            acc[1][1] = __builtin_amdgcn_mfma_f32_16x16x32_f16(a1, b1, acc[1][1], 0, 0, 0);
            acc[1][2] = __builtin_amdgcn_mfma_f32_16x16x32_f16(a1, b2, acc[1][2], 0, 0, 0);
            acc[1][3] = __builtin_amdgcn_mfma_f32_16x16x32_f16(a1, b3, acc[1][3], 0, 0, 0);
            acc[2][0] = __builtin_amdgcn_mfma_f32_16x16x32_f16(a2, b0, acc[2][0], 0, 0, 0);
            acc[2][1] = __builtin_amdgcn_mfma_f32_16x16x32_f16(a2, b1, acc[2][1], 0, 0, 0);
            acc[2][2] = __builtin_amdgcn_mfma_f32_16x16x32_f16(a2, b2, acc[2][2], 0, 0, 0);
            acc[2][3] = __builtin_amdgcn_mfma_f32_16x16x32_f16(a2, b3, acc[2][3], 0, 0, 0);
            acc[3][0] = __builtin_amdgcn_mfma_f32_16x16x32_f16(a3, b0, acc[3][0], 0, 0, 0);
            acc[3][1] = __builtin_amdgcn_mfma_f32_16x16x32_f16(a3, b1, acc[3][1], 0, 0, 0);
            acc[3][2] = __builtin_amdgcn_mfma_f32_16x16x32_f16(a3, b2, acc[3][2], 0, 0, 0);
            acc[3][3] = __builtin_amdgcn_mfma_f32_16x16x32_f16(a3, b3, acc[3][3], 0, 0, 0);
        }
    }

    // Main loop done reading s_e; barrier before aliased s_red writes.
    __syncthreads();

    // 2-stage pairwise cross-wave K-reduction (4 partials -> 2 regions).
    // C/D layout: col = lane&15 (n), row = q*4 + r. Global row = mt*16 + row.
    float* reg = s_red + (kg & 1) * (64 * 68);
    if (kg < 2) {
        #pragma unroll
        for (int mt = 0; mt < 4; ++mt)
            #pragma unroll
            for (int t = 0; t < 4; ++t)
                #pragma unroll
                for (int r = 0; r < 4; ++r)
                    reg[(mt * 16 + q * 4 + r) * 68 + t * 16 + lm] = acc[mt][t][r];
    }
    __syncthreads();
    if (kg >= 2) {
        #pragma unroll
        for (int mt = 0; mt < 4; ++mt)
            #pragma unroll
            for (int t = 0; t < 4; ++t)
                #pragma unroll
                for (int r = 0; r < 4; ++r)
                    reg[(mt * 16 + q * 4 + r) * 68 + t * 16 + lm] += acc[mt][t][r];
    }
    __syncthreads();

    // Epilogue: region0 + region1 + bias, leaky_relu, coalesced f32x4 stores.
    const int row = tid >> 2, c0e = (tid & 3) * 16;
    const int node = m0 + row;
    if (node < N_NODES) {
        #pragma unroll
        for (int i = 0; i < 4; ++i) {
            int c = c0e + i * 4;
            f32x4 v0 = *(const f32x4*)(s_red + row * 68 + c);
            f32x4 v1 = *(const f32x4*)(s_red + 64 * 68 + row * 68 + c);
            f32x4 bb = *(const f32x4*)(bias + c);
            f32x4 o = v0 + v1 + bb;
            #pragma unroll
            for (int jj = 0; jj < 4; ++jj) o[jj] = o[jj] > 0.f ? o[jj] : 0.01f * o[jj];
            *(f32x4*)(out + node * FOUT + c) = o;
        }
    }
}

extern "C" void kernel_launch(void* const* d_in, const int* in_sizes, int n_in,
                              void* d_out, int out_size, void* d_ws, size_t ws_size,
                              hipStream_t stream) {
    const float* h    = (const float*)d_in[0];
    const float* pos  = (const float*)d_in[1];
    const int*   nidx = (const int*)d_in[2];
    const float* w    = (const float*)d_in[3];
    const float* bias = (const float*)d_in[4];
    float* out = (float*)d_out;

    _Float16*      wf   = (_Float16*)d_ws;                        // 256 KB
    unsigned char* hq   = (unsigned char*)d_ws + 262144;          // 3.2 MB
    float4*        posx = (float4*)((char*)d_ws + 262144 + 3200000); // 800 KB

    const int h_blocks = (N_NODES + 255) / 256;                   // 196
    k_prep<<<32 + h_blocks, 256, 0, stream>>>(w, wf, h, hq, pos, posx);
    k_main<<<(N_NODES + MTILE - 1) / MTILE, 256, 0, stream>>>(hq, posx, nidx, wf, bias, out);
}